// Round 6
// baseline (109.993 us; speedup 1.0000x reference)
//
#include <hip/hip_runtime.h>
#include <hip/hip_bf16.h>

#define NB 16384
#define ND 1024
#define NT 20
#define NC 100

#define SPLIT 8                 // K split: each wave covers K=128
#define KW (ND / SPLIT)         // 128
#define SLOTS 13                // 16-row tile slots per (task,kq); stride loop covers rest
#define WAVES (NT * SPLIT * SLOTS)   // 2080
#define BLOCKS (WAVES / 4)           // 520

#define SCALE 4194304.0f        // 2^22 fixed-point (deterministic atomic combine)
#define INV_SCALE (1.0f / 4194304.0f)

typedef __bf16  bf16x8 __attribute__((ext_vector_type(8)));
typedef float   f32x4  __attribute__((ext_vector_type(4)));
typedef unsigned short ushort_t;

__device__ __forceinline__ unsigned int f2bf(float f) {
    unsigned int u = __builtin_bit_cast(unsigned int, f);
    u += 0x7FFFu + ((u >> 16) & 1u);   // RNE
    return u >> 16;
}
__device__ __forceinline__ unsigned long long pack4(float a, float b, float c, float d) {
    return (unsigned long long)f2bf(a)
         | ((unsigned long long)f2bf(b) << 16)
         | ((unsigned long long)f2bf(c) << 32)
         | ((unsigned long long)f2bf(d) << 48);
}
__device__ __forceinline__ bf16x8 mk_frag(float4 a, float4 b) {
    union { unsigned long long u[2]; bf16x8 v; } r;
    r.u[0] = pack4(a.x, a.y, a.z, a.w);
    r.u[1] = pack4(b.x, b.y, b.z, b.w);
    return r.v;
}

// ---------------- bucketing ----------------

__global__ void count_kernel(const int* __restrict__ t, int* __restrict__ counts) {
    __shared__ int h[NT];
    int tid = threadIdx.x;
    if (tid < NT) h[tid] = 0;
    __syncthreads();
    int i = blockIdx.x * 256 + tid;
    atomicAdd(&h[t[i]], 1);
    __syncthreads();
    if (tid < NT && h[tid] > 0) atomicAdd(&counts[tid], h[tid]);
}

__global__ void scan_kernel(const int* __restrict__ counts,
                            int* __restrict__ offsets, int* __restrict__ cursors) {
    if (threadIdx.x == 0) {
        int acc = 0;
        for (int i = 0; i < NT; ++i) {
            offsets[i] = acc; cursors[i] = acc; acc += counts[i];
        }
        offsets[NT] = acc;
    }
}

__global__ void scatter_kernel(const int* __restrict__ t, int* __restrict__ cursors,
                               int* __restrict__ idx_list) {
    __shared__ int h[NT];
    __shared__ int base[NT];
    int tid = threadIdx.x;
    if (tid < NT) h[tid] = 0;
    __syncthreads();
    int i = blockIdx.x * 256 + tid;
    int task = t[i];
    int lpos = atomicAdd(&h[task], 1);
    __syncthreads();
    if (tid < NT && h[tid] > 0) base[tid] = atomicAdd(&cursors[tid], h[tid]);
    __syncthreads();
    idx_list[base[task] + lpos] = i;
}

// ---------------- W f32 -> bf16 pre-convert ----------------

__global__ void wcvt_kernel(const float* __restrict__ W, ushort_t* __restrict__ Wbf) {
    int i = blockIdx.x * 256 + threadIdx.x;          // 8 elems/thread
    const float4* p = (const float4*)(W + (size_t)i * 8);
    float4 a = p[0], b = p[1];
    unsigned long long u0 = pack4(a.x, a.y, a.z, a.w);
    unsigned long long u1 = pack4(b.x, b.y, b.z, b.w);
    uint4 o;
    o.x = (unsigned)u0; o.y = (unsigned)(u0 >> 32);
    o.z = (unsigned)u1; o.w = (unsigned)(u1 >> 32);
    ((uint4*)Wbf)[i] = o;
}

// ---------------- grouped GEMM: B-in-registers, wave-independent ----------
// Wave (task, kq, tile): 16 rows x 112 cols x K=128. B tile (28 x bf16x8 =
// 112 VGPRs) loaded ONCE, held across the m0 loop. Per m0-iter: 8 A loads +
// 4 idx loads + 28 MFMA + 28 fixed-point atomics. A prefetched one iter ahead.

__global__ __launch_bounds__(256, 2) void gemm_kernel(
    const float* __restrict__ x, const ushort_t* __restrict__ Wbf,
    const int* __restrict__ offsets, const int* __restrict__ idx_list,
    int* __restrict__ outi)
{
    const int w     = blockIdx.x * 4 + (threadIdx.x >> 6);
    const int task  = w / (SPLIT * SLOTS);
    const int rem   = w - task * (SPLIT * SLOTS);
    const int kq    = rem / SLOTS;
    const int tile0 = rem - kq * SLOTS;
    const int lane  = threadIdx.x & 63;
    const int csel  = lane & 15;           // A row in tile / B+C col in frag
    const int kb    = (lane >> 4) * 8;     // k offset within 32-block
    const int seg   = offsets[task];
    const int cnt   = offsets[task + 1] - seg;
    const int kbase = kq * KW;

    // ---- B tile resident in registers: Breg[ks][n] ----
    bf16x8 Breg[4][7];
    {
        const ushort_t* wt = Wbf + (size_t)task * NC * ND + kbase + kb;
#pragma unroll
        for (int n = 0; n < 7; ++n) {
            int c = n * 16 + csel; if (c > NC - 1) c = NC - 1;   // pad cols dup row 99
            const ushort_t* bp = wt + (size_t)c * ND;
#pragma unroll
            for (int ks = 0; ks < 4; ++ks)
                Breg[ks][n] = *(const bf16x8*)(bp + ks * 32);
        }
    }

    int m0 = tile0 * 16;
    if (m0 >= cnt) return;
    const int stride = SLOTS * 16;

    // prologue: first A tile
    int mr = m0 + csel; if (mr > cnt - 1) mr = cnt - 1;
    const float* pa = x + (size_t)idx_list[seg + mr] * ND + kbase + kb;
    float4 a[8];
#pragma unroll
    for (int ks = 0; ks < 4; ++ks) {
        a[2 * ks]     = *(const float4*)(pa + ks * 32);
        a[2 * ks + 1] = *(const float4*)(pa + ks * 32 + 4);
    }

    for (; m0 < cnt; m0 += stride) {
        // convert current A to MFMA frags
        bf16x8 af[4];
#pragma unroll
        for (int ks = 0; ks < 4; ++ks) af[ks] = mk_frag(a[2 * ks], a[2 * ks + 1]);

        // prefetch next A tile (loop-carried: cannot be sunk past backedge)
        int m0n = m0 + stride;
        if (m0n < cnt) {
            int mrn = m0n + csel; if (mrn > cnt - 1) mrn = cnt - 1;
            const float* pan = x + (size_t)idx_list[seg + mrn] * ND + kbase + kb;
#pragma unroll
            for (int ks = 0; ks < 4; ++ks) {
                a[2 * ks]     = *(const float4*)(pan + ks * 32);
                a[2 * ks + 1] = *(const float4*)(pan + ks * 32 + 4);
            }
        }

        // output row indices for this tile
        int oi[4];
#pragma unroll
        for (int rr = 0; rr < 4; ++rr) {
            int gm = m0 + (lane >> 4) * 4 + rr;
            oi[rr] = (gm < cnt) ? idx_list[seg + gm] : -1;
        }

        f32x4 acc[7];
#pragma unroll
        for (int n = 0; n < 7; ++n) acc[n] = (f32x4){0.f, 0.f, 0.f, 0.f};

#pragma unroll
        for (int ks = 0; ks < 4; ++ks)
#pragma unroll
            for (int n = 0; n < 7; ++n)
                acc[n] = __builtin_amdgcn_mfma_f32_16x16x32_bf16(af[ks], Breg[ks][n],
                                                                 acc[n], 0, 0, 0);

        // fixed-point atomic accumulate (order-independent, deterministic)
#pragma unroll
        for (int n = 0; n < 7; ++n) {
            int c = n * 16 + csel;
            if (c < NC) {
#pragma unroll
                for (int rr = 0; rr < 4; ++rr)
                    if (oi[rr] >= 0)
                        atomicAdd(&outi[(size_t)oi[rr] * NC + c],
                                  __float2int_rn(acc[n][rr] * SCALE));
            }
        }
    }
}

// ---------------- finalize: fixed-point -> float, + bias ----------------

__global__ void finalize_kernel(int* __restrict__ io, const int* __restrict__ t,
                                const float* __restrict__ bias) {
    int id = blockIdx.x * 256 + threadIdx.x;     // NB*NC/2 threads
    int2 v = ((const int2*)io)[id];
    int e0 = 2 * id;
    int oi = e0 / NC;
    int c  = e0 - oi * NC;                        // even, c+1 <= 99
    const float* brow = bias + t[oi] * NC;
    float2 o;
    o.x = (float)v.x * INV_SCALE + brow[c];
    o.y = (float)v.y * INV_SCALE + brow[c + 1];
    ((float2*)io)[id] = o;
}

// ---------------- launch ----------------

extern "C" void kernel_launch(void* const* d_in, const int* in_sizes, int n_in,
                              void* d_out, int out_size, void* d_ws, size_t ws_size,
                              hipStream_t stream) {
    const float* x    = (const float*)d_in[0];
    const int*   t    = (const int*)d_in[1];
    const float* W    = (const float*)d_in[2];
    const float* bias = (const float*)d_in[3];

    char* ws = (char*)d_ws;
    int* counts   = (int*)ws;                    // 32 ints
    int* offsets  = (int*)(ws + 128);            // 21 ints
    int* cursors  = (int*)(ws + 256);            // 20 ints
    int* idx_list = (int*)(ws + 384);            // NB ints -> ends at 65920
    ushort_t* Wbf = (ushort_t*)(ws + 69632);     // 4,096,000 B

    hipMemsetAsync(counts, 0, 32 * sizeof(int), stream);
    hipMemsetAsync(d_out, 0, (size_t)NB * NC * sizeof(int), stream);
    wcvt_kernel    <<<NT * NC * ND / (256 * 8), 256, 0, stream>>>(W, Wbf);
    count_kernel   <<<NB / 256, 256, 0, stream>>>(t, counts);
    scan_kernel    <<<1, 64, 0, stream>>>(counts, offsets, cursors);
    scatter_kernel <<<NB / 256, 256, 0, stream>>>(t, cursors, idx_list);
    gemm_kernel    <<<BLOCKS, 256, 0, stream>>>(x, Wbf, offsets, idx_list, (int*)d_out);
    finalize_kernel<<<NB * NC / 512, 256, 0, stream>>>((int*)d_out, t, bias);
}

// Round 7
// 66.318 us; speedup vs baseline: 1.6586x; 1.6586x over previous
//
#include <hip/hip_runtime.h>
#include <hip/hip_bf16.h>

#define NB 16384
#define ND 1024
#define NT 20
#define NC 100

#define NTILES_MAX 1044        // sum ceil(cnt_t/16) <= 1042; padded
#define KW 256                 // K per wave (4 waves cover ND=1024)

typedef __bf16  bf16x8 __attribute__((ext_vector_type(8)));
typedef float   f32x4  __attribute__((ext_vector_type(4)));
typedef unsigned short ushort_t;

__device__ __forceinline__ unsigned int f2bf(float f) {
    unsigned int u = __builtin_bit_cast(unsigned int, f);
    u += 0x7FFFu + ((u >> 16) & 1u);   // RNE
    return u >> 16;
}
__device__ __forceinline__ unsigned long long pack4(float a, float b, float c, float d) {
    return (unsigned long long)f2bf(a)
         | ((unsigned long long)f2bf(b) << 16)
         | ((unsigned long long)f2bf(c) << 32)
         | ((unsigned long long)f2bf(d) << 48);
}
__device__ __forceinline__ bf16x8 mk_frag(float4 a, float4 b) {
    union { unsigned long long u[2]; bf16x8 v; } r;
    r.u[0] = pack4(a.x, a.y, a.z, a.w);
    r.u[1] = pack4(b.x, b.y, b.z, b.w);
    return r.v;
}

// ---------------- fused bucketing: count + scan + tile table + scatter ------
// Single block, 1024 threads. idx_list permutation within a task may vary
// run-to-run (LDS atomic order), but every output row's value is computed
// from its own x-row and task W only -> bitwise-identical output regardless.

__global__ void bucket_kernel(const int* __restrict__ t, int* __restrict__ offsets,
                              int* __restrict__ tiles, int* __restrict__ idx_list) {
    __shared__ int h[NT], off[NT + 1], cur[NT], tb[NT + 1];
    const int tid = threadIdx.x;
    if (tid < NT) h[tid] = 0;
    __syncthreads();
#pragma unroll
    for (int k = 0; k < NB / 1024; ++k)
        atomicAdd(&h[t[tid + k * 1024]], 1);
    __syncthreads();
    if (tid == 0) {
        int acc = 0, tbv = 0;
        for (int i = 0; i < NT; ++i) {
            off[i] = acc; cur[i] = acc; tb[i] = tbv;
            acc += h[i]; tbv += (h[i] + 15) >> 4;
        }
        off[NT] = acc; tb[NT] = tbv;
    }
    __syncthreads();
    if (tid <= NT) offsets[tid] = off[tid];
    // tile table: entry = (task<<16) | tile_index_within_task, -1 = inactive
    const int ntiles = tb[NT];
    for (int g = tid; g < NTILES_MAX; g += 1024) {
        int e = -1;
        if (g < ntiles) {
            int task = 0;
            while (tb[task + 1] <= g) ++task;
            e = (task << 16) | (g - tb[task]);
        }
        tiles[g] = e;
    }
    // scatter
#pragma unroll
    for (int k = 0; k < NB / 1024; ++k) {
        int i = tid + k * 1024;
        idx_list[atomicAdd(&cur[t[i]], 1)] = i;
    }
}

// ---------------- W f32 -> bf16 pre-convert ----------------

__global__ void wcvt_kernel(const float* __restrict__ W, ushort_t* __restrict__ Wbf) {
    int i = blockIdx.x * 256 + threadIdx.x;          // 8 elems/thread
    const float4* p = (const float4*)(W + (size_t)i * 8);
    float4 a = p[0], b = p[1];
    unsigned long long u0 = pack4(a.x, a.y, a.z, a.w);
    unsigned long long u1 = pack4(b.x, b.y, b.z, b.w);
    uint4 o;
    o.x = (unsigned)u0; o.y = (unsigned)(u0 >> 32);
    o.z = (unsigned)u1; o.w = (unsigned)(u1 >> 32);
    ((uint4*)Wbf)[i] = o;
}

// ---------------- grouped GEMM: block = one 16-row tile, waves = K-quarters -
// Wave kq handles K in [kq*256, +256): 8 k-steps of {2 A f32x4 + 7 B bf16x8
// loads, 7 MFMA}. Partials combined via LDS tree (fixed order, deterministic),
// wave 0 adds bias and stores f32 directly. No atomics, no LDS staging of
// operands, no barriers in the K loop -> latency hidden purely by ~16-20
// waves/CU of TLP.

__global__ __launch_bounds__(256, 4) void gemm_kernel(
    const float* __restrict__ x, const ushort_t* __restrict__ Wbf,
    const float* __restrict__ bias, const int* __restrict__ offsets,
    const int* __restrict__ tiles, const int* __restrict__ idx_list,
    float* __restrict__ out)
{
    __shared__ float red[3][64][29];     // stride 29: bank-conflict-free
    const int ent = tiles[blockIdx.x];
    if (ent < 0) return;
    const int task = ent >> 16;
    const int m0   = (ent & 0xffff) << 4;
    const int seg  = offsets[task];
    const int cnt  = offsets[task + 1] - seg;

    const int wave = threadIdx.x >> 6;
    const int lane = threadIdx.x & 63;
    const int csel = lane & 15;          // A row in tile / B+C col in frag
    const int q    = lane >> 4;
    const int kb   = q * 8;
    const int kbase = wave * KW;

    // B fragment pointers (7 col-groups, clamped pad cols)
    const ushort_t* wt = Wbf + (size_t)task * NC * ND + kbase + kb;
    const ushort_t* bp[7];
#pragma unroll
    for (int n = 0; n < 7; ++n) {
        int c = n * 16 + csel; if (c > NC - 1) c = NC - 1;
        bp[n] = wt + (size_t)c * ND;
    }
    // A row pointer (clamped tail rows; results discarded at store)
    int mr = m0 + csel; if (mr > cnt - 1) mr = cnt - 1;
    const float* pa = x + (size_t)idx_list[seg + mr] * ND + kbase + kb;

    f32x4 acc[7];
#pragma unroll
    for (int n = 0; n < 7; ++n) acc[n] = (f32x4){0.f, 0.f, 0.f, 0.f};

#pragma unroll
    for (int kk = 0; kk < KW / 32; ++kk) {
        float4 a0 = *(const float4*)(pa + kk * 32);
        float4 a1 = *(const float4*)(pa + kk * 32 + 4);
        bf16x8 af = mk_frag(a0, a1);
#pragma unroll
        for (int n = 0; n < 7; ++n) {
            bf16x8 bf = *(const bf16x8*)(bp[n] + kk * 32);
            acc[n] = __builtin_amdgcn_mfma_f32_16x16x32_bf16(af, bf, acc[n], 0, 0, 0);
        }
    }

    // K-split combine: waves 1-3 publish, wave 0 sums in fixed order
    if (wave) {
#pragma unroll
        for (int n = 0; n < 7; ++n)
#pragma unroll
            for (int rr = 0; rr < 4; ++rr)
                red[wave - 1][lane][n * 4 + rr] = acc[n][rr];
    }
    __syncthreads();
    if (wave == 0) {
        int oi[4];
#pragma unroll
        for (int rr = 0; rr < 4; ++rr) {
            int gm = m0 + q * 4 + rr;
            oi[rr] = (gm < cnt) ? idx_list[seg + gm] : -1;
        }
#pragma unroll
        for (int n = 0; n < 7; ++n) {
            int c = n * 16 + csel;
            if (c < NC) {
                float bv = bias[task * NC + c];
#pragma unroll
                for (int rr = 0; rr < 4; ++rr) {
                    float v = acc[n][rr] + red[0][lane][n * 4 + rr]
                                         + red[1][lane][n * 4 + rr]
                                         + red[2][lane][n * 4 + rr];
                    if (oi[rr] >= 0)
                        out[(size_t)oi[rr] * NC + c] = v + bv;
                }
            }
        }
    }
}

// ---------------- launch ----------------

extern "C" void kernel_launch(void* const* d_in, const int* in_sizes, int n_in,
                              void* d_out, int out_size, void* d_ws, size_t ws_size,
                              hipStream_t stream) {
    const float* x    = (const float*)d_in[0];
    const int*   t    = (const int*)d_in[1];
    const float* W    = (const float*)d_in[2];
    const float* bias = (const float*)d_in[3];

    char* ws = (char*)d_ws;
    int* offsets  = (int*)ws;                    // 21 ints   @ 0
    int* tiles    = (int*)(ws + 128);            // 1044 ints @ 128..4304
    int* idx_list = (int*)(ws + 4352);           // 16384 ints -> ends 69888
    ushort_t* Wbf = (ushort_t*)(ws + 69888);     // 4,096,000 B (16B aligned)

    wcvt_kernel  <<<NT * NC * ND / (256 * 8), 256, 0, stream>>>(W, Wbf);
    bucket_kernel<<<1, 1024, 0, stream>>>(t, offsets, tiles, idx_list);
    gemm_kernel  <<<NTILES_MAX, 256, 0, stream>>>(x, Wbf, bias, offsets, tiles,
                                                  idx_list, (float*)d_out);
}

// Round 8
// 54.599 us; speedup vs baseline: 2.0145x; 1.2146x over previous
//
#include <hip/hip_runtime.h>
#include <hip/hip_bf16.h>

#define NB 16384
#define ND 1024
#define NT 20
#define NC 100

#define NTILES_MAX 1044        // sum ceil(cnt_t/16) <= 1042; padded

typedef __bf16  bf16x8 __attribute__((ext_vector_type(8)));
typedef float   f32x4  __attribute__((ext_vector_type(4)));
typedef unsigned short ushort_t;

__device__ __forceinline__ unsigned int f2bf(float f) {
    unsigned int u = __builtin_bit_cast(unsigned int, f);
    u += 0x7FFFu + ((u >> 16) & 1u);   // RNE
    return u >> 16;
}
__device__ __forceinline__ unsigned long long pack4(float a, float b, float c, float d) {
    return (unsigned long long)f2bf(a)
         | ((unsigned long long)f2bf(b) << 16)
         | ((unsigned long long)f2bf(c) << 32)
         | ((unsigned long long)f2bf(d) << 48);
}

// ---------------- fused bucketing ----------------
// Single block, 1024 threads. Output is invariant to idx_list permutation
// within a task (each row's value depends only on its own x-row + task W).

__global__ void bucket_kernel(const int* __restrict__ t, int* __restrict__ offsets,
                              int* __restrict__ tiles, int* __restrict__ idx_list) {
    __shared__ int h[NT], off[NT + 1], cur[NT], tb[NT + 1];
    const int tid = threadIdx.x;
    if (tid < NT) h[tid] = 0;
    __syncthreads();
    const int4* t4 = (const int4*)t;
    int4 v[4];
#pragma unroll
    for (int k = 0; k < 4; ++k) v[k] = t4[tid + k * 1024];   // all issued upfront
#pragma unroll
    for (int k = 0; k < 4; ++k) {
        atomicAdd(&h[v[k].x], 1); atomicAdd(&h[v[k].y], 1);
        atomicAdd(&h[v[k].z], 1); atomicAdd(&h[v[k].w], 1);
    }
    __syncthreads();
    if (tid == 0) {
        int acc = 0, tv = 0;
        for (int i = 0; i < NT; ++i) {
            off[i] = acc; cur[i] = acc; tb[i] = tv;
            acc += h[i]; tv += (h[i] + 15) >> 4;
        }
        off[NT] = acc; tb[NT] = tv;
    }
    __syncthreads();
    if (tid <= NT) offsets[tid] = off[tid];
    const int ntiles = tb[NT];
    for (int g = tid; g < NTILES_MAX; g += 1024) {
        int e = -1;
        if (g < ntiles) {
            int task = 0;
            while (tb[task + 1] <= g) ++task;
            e = (task << 16) | (g - tb[task]);
        }
        tiles[g] = e;
    }
#pragma unroll
    for (int k = 0; k < 4; ++k) {
        int base = (tid + k * 1024) * 4;
        idx_list[atomicAdd(&cur[v[k].x], 1)] = base;
        idx_list[atomicAdd(&cur[v[k].y], 1)] = base + 1;
        idx_list[atomicAdd(&cur[v[k].z], 1)] = base + 2;
        idx_list[atomicAdd(&cur[v[k].w], 1)] = base + 3;
    }
}

// ---------------- W f32 -> bf16, MFMA-fragment-packed ----------------
// Wfrag block (task, kkg, n) = 512 ushorts: lane l (0..63) holds 8 bf16 of
// col c = n*16 + (l&15), k = kkg*32 + (l>>4)*8 .. +8.  -> GEMM B-load is one
// contiguous 1KB instruction. Pad cols (100..111) written as zeros.

__global__ void wcvt_kernel(const float* __restrict__ W, ushort_t* __restrict__ Wf) {
    int g = blockIdx.x * 256 + threadIdx.x;     // 20*112*128 = 286720 threads
    int kg   = g & 127;                         // 8-elem k-group
    int rest = g >> 7;
    int c    = rest % 112;
    int task = rest / 112;
    unsigned long long u0 = 0, u1 = 0;
    if (c < NC) {
        const float* p = W + ((size_t)(task * NC + c)) * ND + kg * 8;
        float4 a = *(const float4*)p;
        float4 b = *(const float4*)(p + 4);
        u0 = pack4(a.x, a.y, a.z, a.w);
        u1 = pack4(b.x, b.y, b.z, b.w);
    }
    size_t dst = (((size_t)task * 32 + (kg >> 2)) * 7 + (c >> 4)) * 512
               + (size_t)((c & 15) | ((kg & 3) << 4)) * 8;
    *(unsigned long long*)(Wf + dst)     = u0;
    *(unsigned long long*)(Wf + dst + 4) = u1;
}

// ---------------- grouped GEMM ----------------
// Block = one 16-row tile. Stage: each wave loads 4 whole x-rows with
// contiguous 1KB instructions, converts to bf16 into XOR-swizzled LDS
// [16][2048B]. One barrier. Compute: wave kq covers K in [kq*256,+256):
// 8 k-blocks of {1 ds_read_b128 A-frag + 7 contiguous 1KB B-frag loads +
// 7 MFMA}. Combine K-split via LDS tree (reusing A buffer), wave 0 stores.

__global__ __launch_bounds__(256, 4) void gemm_kernel(
    const float* __restrict__ x, const ushort_t* __restrict__ Wfrag,
    const float* __restrict__ bias, const int* __restrict__ offsets,
    const int* __restrict__ tiles, const int* __restrict__ idx_list,
    float* __restrict__ out)
{
    __shared__ __align__(16) char lds[32768];
    const int ent = tiles[blockIdx.x];
    if (ent < 0) return;
    const int task = ent >> 16;
    const int m0   = (ent & 0xffff) << 4;
    const int seg  = offsets[task];
    const int cnt  = offsets[task + 1] - seg;

    const int wave = threadIdx.x >> 6;
    const int lane = threadIdx.x & 63;
    const int csel = lane & 15;
    const int q    = lane >> 4;

    // ---- stage A: wave w stages rows 4w..4w+3 ----
    int rows[4];
#pragma unroll
    for (int j = 0; j < 4; ++j) {
        int mr = m0 + wave * 4 + j; if (mr > cnt - 1) mr = cnt - 1;
        rows[j] = idx_list[seg + mr];
    }
    float4 ar[16];
#pragma unroll
    for (int j = 0; j < 4; ++j) {
        const float* px = x + (size_t)rows[j] * ND;
#pragma unroll
        for (int qq = 0; qq < 4; ++qq)
            ar[j * 4 + qq] = *(const float4*)(px + qq * 256 + lane * 4);  // 1KB contiguous
    }
#pragma unroll
    for (int j = 0; j < 4; ++j) {
        int rl = wave * 4 + j;
        unsigned swz = (unsigned)((rl & 7) << 4);
        char* rowb = lds + rl * 2048;
#pragma unroll
        for (int qq = 0; qq < 4; ++qq) {
            float4 v = ar[j * 4 + qq];
            *(unsigned long long*)(rowb + (((unsigned)(qq * 512 + lane * 8)) ^ swz)) =
                pack4(v.x, v.y, v.z, v.w);
        }
    }
    __syncthreads();

    // ---- compute: wave = kq ----
    const ushort_t* bb = Wfrag + ((size_t)(task * 32 + wave * 8) * 7) * 512 + lane * 8;
    f32x4 acc[7];
#pragma unroll
    for (int n = 0; n < 7; ++n) acc[n] = (f32x4){0.f, 0.f, 0.f, 0.f};

    const unsigned aswz = (unsigned)((csel & 7) << 4);
    const char* arow = lds + csel * 2048;
#pragma unroll
    for (int kk = 0; kk < 8; ++kk) {
        bf16x8 af = *(const bf16x8*)(arow +
            (((unsigned)(wave * 512 + kk * 64 + q * 16)) ^ aswz));
#pragma unroll
        for (int n = 0; n < 7; ++n) {
            bf16x8 bf = *(const bf16x8*)(bb + (kk * 7 + n) * 512);   // 1KB contiguous
            acc[n] = __builtin_amdgcn_mfma_f32_16x16x32_bf16(af, bf, acc[n], 0, 0, 0);
        }
    }

    // ---- K-split combine (reuse A-LDS), wave 0 stores ----
    __syncthreads();                       // all A-frag reads done
    float (*red)[64][29] = (float (*)[64][29])lds;
    if (wave) {
#pragma unroll
        for (int n = 0; n < 7; ++n)
#pragma unroll
            for (int rr = 0; rr < 4; ++rr)
                red[wave - 1][lane][n * 4 + rr] = acc[n][rr];
    }
    __syncthreads();
    if (wave == 0) {
        int oi[4];
#pragma unroll
        for (int rr = 0; rr < 4; ++rr) {
            int gm = m0 + q * 4 + rr;
            oi[rr] = (gm < cnt) ? idx_list[seg + gm] : -1;
        }
#pragma unroll
        for (int n = 0; n < 7; ++n) {
            int c = n * 16 + csel;
            if (c < NC) {
                float bv = bias[task * NC + c];
#pragma unroll
                for (int rr = 0; rr < 4; ++rr) {
                    float v = acc[n][rr] + red[0][lane][n * 4 + rr]
                                         + red[1][lane][n * 4 + rr]
                                         + red[2][lane][n * 4 + rr];
                    if (oi[rr] >= 0)
                        out[(size_t)oi[rr] * NC + c] = v + bv;
                }
            }
        }
    }
}

// ---------------- launch ----------------

extern "C" void kernel_launch(void* const* d_in, const int* in_sizes, int n_in,
                              void* d_out, int out_size, void* d_ws, size_t ws_size,
                              hipStream_t stream) {
    const float* x    = (const float*)d_in[0];
    const int*   t    = (const int*)d_in[1];
    const float* W    = (const float*)d_in[2];
    const float* bias = (const float*)d_in[3];

    char* ws = (char*)d_ws;
    int* offsets   = (int*)ws;                   // 21 ints   @ 0
    int* tiles     = (int*)(ws + 128);           // 1044 ints @ 128..4304
    int* idx_list  = (int*)(ws + 4352);          // 16384 ints -> ends 69888
    ushort_t* Wfrg = (ushort_t*)(ws + 69888);    // 4,587,520 B (16B aligned)

    wcvt_kernel  <<<20 * 112 * 128 / 256, 256, 0, stream>>>(W, Wfrg);
    bucket_kernel<<<1, 1024, 0, stream>>>(t, offsets, tiles, idx_list);
    gemm_kernel  <<<NTILES_MAX, 256, 0, stream>>>(x, Wfrg, bias, offsets, tiles,
                                                  idx_list, (float*)d_out);
}

// Round 10
// 41.694 us; speedup vs baseline: 2.6381x; 1.3095x over previous
//
#include <hip/hip_runtime.h>
#include <hip/hip_bf16.h>

#define NB 16384
#define ND 1024
#define NT 20
#define NC 100
#define NTILES_MAX 532         // 32-row tiles: sum ceil(cnt_t/32) <= 531
#define STEPS 16               // K steps of BK=64
#define ABUF 8192              // 32 rows x 64 f32 x 4B
#define BBUF 14336             // 14 fragment blocks x 1KB
#define BUFB (ABUF + BBUF)     // 22528

typedef __bf16  bf16x8 __attribute__((ext_vector_type(8)));
typedef float   f32x4  __attribute__((ext_vector_type(4)));
typedef unsigned short ushort_t;

__device__ __forceinline__ unsigned int f2bf(float f) {
    unsigned int u = __builtin_bit_cast(unsigned int, f);
    u += 0x7FFFu + ((u >> 16) & 1u);   // RNE
    return u >> 16;
}
__device__ __forceinline__ unsigned long long pack4(float a, float b, float c, float d) {
    return (unsigned long long)f2bf(a)
         | ((unsigned long long)f2bf(b) << 16)
         | ((unsigned long long)f2bf(c) << 32)
         | ((unsigned long long)f2bf(d) << 48);
}
__device__ __forceinline__ bf16x8 mk_frag(float4 a, float4 b) {
    union { unsigned long long u[2]; bf16x8 v; } r;
    r.u[0] = pack4(a.x, a.y, a.z, a.w);
    r.u[1] = pack4(b.x, b.y, b.z, b.w);
    return r.v;
}

// async 16B/lane global->LDS; LDS dest = wave-uniform base + lane*16 (HW)
__device__ __forceinline__ void async_cp16(const void* g, void* l) {
    auto gp = reinterpret_cast<const __attribute__((address_space(1))) unsigned int*>(
        reinterpret_cast<unsigned long long>(g));
    auto lp = reinterpret_cast<__attribute__((address_space(3))) unsigned int*>(
        static_cast<unsigned int>(reinterpret_cast<unsigned long long>(l)));
    __builtin_amdgcn_global_load_lds(gp, lp, 16, 0, 0);
}

// ---------------- fused bucketing (R8-verified; 32-row tiles) ----------------

__global__ void bucket_kernel(const int* __restrict__ t, int* __restrict__ offsets,
                              int* __restrict__ tiles, int* __restrict__ idx_list) {
    __shared__ int h[NT], off[NT + 1], cur[NT], tb[NT + 1];
    const int tid = threadIdx.x;
    if (tid < NT) h[tid] = 0;
    __syncthreads();
    const int4* t4 = (const int4*)t;
    int4 v[4];
#pragma unroll
    for (int k = 0; k < 4; ++k) v[k] = t4[tid + k * 1024];
#pragma unroll
    for (int k = 0; k < 4; ++k) {
        atomicAdd(&h[v[k].x], 1); atomicAdd(&h[v[k].y], 1);
        atomicAdd(&h[v[k].z], 1); atomicAdd(&h[v[k].w], 1);
    }
    __syncthreads();
    if (tid == 0) {
        int acc = 0, tv = 0;
        for (int i = 0; i < NT; ++i) {
            off[i] = acc; cur[i] = acc; tb[i] = tv;
            acc += h[i]; tv += (h[i] + 31) >> 5;
        }
        off[NT] = acc; tb[NT] = tv;
    }
    __syncthreads();
    if (tid <= NT) offsets[tid] = off[tid];
    const int ntiles = tb[NT];
    for (int g = tid; g < NTILES_MAX; g += 1024) {
        int e = -1;
        if (g < ntiles) {
            int task = 0;
            while (tb[task + 1] <= g) ++task;
            e = (task << 16) | (g - tb[task]);
        }
        tiles[g] = e;
    }
#pragma unroll
    for (int k = 0; k < 4; ++k) {
        int base = (tid + k * 1024) * 4;
        idx_list[atomicAdd(&cur[v[k].x], 1)] = base;
        idx_list[atomicAdd(&cur[v[k].y], 1)] = base + 1;
        idx_list[atomicAdd(&cur[v[k].z], 1)] = base + 2;
        idx_list[atomicAdd(&cur[v[k].w], 1)] = base + 3;
    }
}

// ---------------- W f32 -> bf16, MFMA-fragment-packed (R8-verified) ---------
// Block (task, kkg, n) = 512 ushorts; lane l holds col c=n*16+(l&15),
// k = kkg*32 + (l>>4)*8 .. +8. Pad cols (100..111) zeroed.

__global__ void wcvt_kernel(const float* __restrict__ W, ushort_t* __restrict__ Wf) {
    int g = blockIdx.x * 256 + threadIdx.x;     // 20*112*128 threads
    int kg   = g & 127;
    int rest = g >> 7;
    int c    = rest % 112;
    int task = rest / 112;
    unsigned long long u0 = 0, u1 = 0;
    if (c < NC) {
        const float* p = W + ((size_t)(task * NC + c)) * ND + kg * 8;
        float4 a = *(const float4*)p;
        float4 b = *(const float4*)(p + 4);
        u0 = pack4(a.x, a.y, a.z, a.w);
        u1 = pack4(b.x, b.y, b.z, b.w);
    }
    size_t dst = (((size_t)task * 32 + (kg >> 2)) * 7 + (c >> 4)) * 512
               + (size_t)((c & 15) | ((kg & 3) << 4)) * 8;
    *(unsigned long long*)(Wf + dst)     = u0;
    *(unsigned long long*)(Wf + dst + 4) = u1;
}

// ---------------- grouped GEMM: R4-verified async skeleton, no split-K ------
// Block = 32 rows x 112 cols x K=1024. 4 waves = (wm row-group 16) x (wn
// frag-group: wn=0 frags 0-3, wn=1 frags 4-6). Per step (BK=64): stage next
// A (8 x 1KB async, inverse-swizzled f32 source) + B (14 x 1KB async,
// fragment-packed, lane-linear, no swizzle). Double-buffered with R4's
// verified lgkmcnt/barrier/vmcnt(6) schedule. Direct f32 store + bias.

__global__ __launch_bounds__(256, 3) void gemm_kernel(
    const float* __restrict__ x, const ushort_t* __restrict__ Wfrag,
    const float* __restrict__ bias, const int* __restrict__ offsets,
    const int* __restrict__ tiles, const int* __restrict__ idx_list,
    float* __restrict__ out)
{
    __shared__ __align__(16) char lds[2 * BUFB];
    const int ent = tiles[blockIdx.x];
    if (ent < 0) return;
    const int task = ent >> 16;
    const int m0   = (ent & 0xffff) << 5;
    const int seg  = offsets[task];
    const int cnt  = offsets[task + 1] - seg;

    const int tid  = threadIdx.x;
    const int wid  = tid >> 6;
    const int lane = tid & 63;
    const int wm   = wid >> 1;          // row-group
    const int wn   = wid & 1;           // frag-group
    const int csel = lane & 15;
    const int q    = lane >> 4;

    // A staging sources: instr j = 2*wid + jj covers rows j*4..j*4+3
    const float* srcA[2];
#pragma unroll
    for (int jj = 0; jj < 2; ++jj) {
        int j    = 2 * wid + jj;
        int row  = j * 4 + q;
        int byte = csel * 16;
        int logb = byte ^ ((row & 7) << 4);     // inverse-swizzled source
        int sr   = m0 + row; if (sr > cnt - 1) sr = cnt - 1;
        srcA[jj] = x + (size_t)idx_list[seg + sr] * ND + (logb >> 2);
    }
    // B staging: fragment-packed, lane-linear source; slots ii = kkb*7+frag
    const ushort_t* srcB = Wfrag + (size_t)task * (32 * 7 * 512) + lane * 8;
    int bii[4];
#pragma unroll
    for (int jj = 0; jj < 4; ++jj) {
        int i = wid + 4 * jj;
        bii[jj] = (i < 14) ? i : (i - 14);   // 2 dup stages: identical data, benign
    }

    auto STAGE = [&](int s) {
        char* Ab = lds + (s & 1) * BUFB;
        char* Bb = Ab + ABUF;
        async_cp16(srcA[0] + s * 64, Ab + (2 * wid + 0) * 1024);
        async_cp16(srcA[1] + s * 64, Ab + (2 * wid + 1) * 1024);
#pragma unroll
        for (int jj = 0; jj < 4; ++jj)
            async_cp16(srcB + (size_t)(s * 14 + bii[jj]) * 512, Bb + bii[jj] * 1024);
    };

    const int rowA = wm * 16 + csel;
    const unsigned swzA = (unsigned)((rowA & 7) << 4);
    const int nfr = wn ? 3 : 4;
    f32x4 acc[4] = {};

    auto COMPUTE = [&](int s) {
        const char* Ab = lds + (s & 1) * BUFB;
        const char* Bb = Ab + ABUF;
        const char* Ar = Ab + rowA * 256;
#pragma unroll
        for (int kkb = 0; kkb < 2; ++kkb) {
            unsigned abase = (unsigned)(kkb * 128 + q * 32);
            float4 a0 = *(const float4*)(Ar + (abase ^ swzA));
            float4 a1 = *(const float4*)(Ar + ((abase + 16) ^ swzA));
            bf16x8 af = mk_frag(a0, a1);
#pragma unroll
            for (int nf = 0; nf < 4; ++nf) {
                if (nf < nfr) {
                    int f = wn * 4 + nf;
                    bf16x8 bf = *(const bf16x8*)(Bb + (kkb * 7 + f) * 1024 + lane * 16);
                    acc[nf] = __builtin_amdgcn_mfma_f32_16x16x32_bf16(af, bf, acc[nf], 0, 0, 0);
                }
            }
        }
    };

    // prologue (R4-verified shape)
    STAGE(0);
    STAGE(1);
    asm volatile("s_waitcnt vmcnt(6)" ::: "memory");   // my STAGE(0) landed
    __builtin_amdgcn_sched_barrier(0);
    __builtin_amdgcn_s_barrier();                      // everyone's STAGE(0) landed

#pragma unroll 1
    for (int s = 0; s < STEPS; ++s) {
        COMPUTE(s);
        if (s == STEPS - 1) break;
        asm volatile("s_waitcnt lgkmcnt(0)" ::: "memory");   // my buf-s reads done
        __builtin_amdgcn_s_barrier();                        // all buf-s reads done
        if (s < STEPS - 2) {
            STAGE(s + 2);                                    // overwrite buf s&1
            asm volatile("s_waitcnt vmcnt(6)" ::: "memory"); // STAGE(s+1) landed
        } else {
            asm volatile("s_waitcnt vmcnt(0)" ::: "memory"); // last stage landed
        }
        __builtin_amdgcn_sched_barrier(0);
        __builtin_amdgcn_s_barrier();
    }

    // epilogue: direct store + bias (no split-K -> no combine, no atomics)
    int oi[4];
#pragma unroll
    for (int rr = 0; rr < 4; ++rr) {
        int gm = m0 + wm * 16 + q * 4 + rr;
        oi[rr] = (gm < cnt) ? idx_list[seg + gm] : -1;
    }
#pragma unroll
    for (int nf = 0; nf < 4; ++nf) {
        if (nf < nfr) {
            int cg = (wn * 4 + nf) * 16 + csel;
            if (cg < NC) {
                float bv = bias[task * NC + cg];
#pragma unroll
                for (int rr = 0; rr < 4; ++rr)
                    if (oi[rr] >= 0)
                        out[(size_t)oi[rr] * NC + cg] = acc[nf][rr] + bv;
            }
        }
    }
}

// ---------------- launch ----------------

extern "C" void kernel_launch(void* const* d_in, const int* in_sizes, int n_in,
                              void* d_out, int out_size, void* d_ws, size_t ws_size,
                              hipStream_t stream) {
    const float* x    = (const float*)d_in[0];
    const int*   t    = (const int*)d_in[1];
    const float* W    = (const float*)d_in[2];
    const float* bias = (const float*)d_in[3];

    char* ws = (char*)d_ws;
    int* offsets  = (int*)ws;                    // 21 ints  @ 0
    int* tiles    = (int*)(ws + 128);            // 532 ints -> ends 2256
    int* idx_list = (int*)(ws + 4352);           // 16384 ints -> ends 69888
    ushort_t* Wf  = (ushort_t*)(ws + 69888);     // 4,587,520 B

    wcvt_kernel  <<<20 * 112 * 128 / 256, 256, 0, stream>>>(W, Wf);
    bucket_kernel<<<1, 1024, 0, stream>>>(t, offsets, tiles, idx_list);
    gemm_kernel  <<<NTILES_MAX, 256, 0, stream>>>(x, Wf, bias, offsets, tiles,
                                                  idx_list, (float*)d_out);
}